// Round 4
// baseline (149.545 us; speedup 1.0000x reference)
//
#include <hip/hip_runtime.h>
#include <stdint.h>

#define BATCH 32
#define NH    32
#define KVH   8
#define QPK   4
#define DH    128
#define BS    128
#define NEG   (-1e30f)
#define SCALEF 0.08838834764831845f  // 1/sqrt(128)
#define MAXU  512
#define SPLIT 2
#define CHK   16
#define KVROW (KVH * DH)

#define GAS __attribute__((address_space(1)))
#define LAS __attribute__((address_space(3)))

// Issue 8 coalesced V float4 loads (chunk = 16 tokens) into register array VR.
// Lane covers d-granule r32 of tokens {TT + 2tp + half}.
#define LOAD_V(PB, TT, VR) do {                                                 \
  const float* vb_ = value_cache + ((size_t)(PB) * BS + (TT) + half) * KVROW    \
                   + g * DH + r32 * 4;                                          \
  _Pragma("unroll")                                                             \
  for (int tp = 0; tp < 8; ++tp)                                                \
    VR[tp] = *(const float4*)&vb_[(size_t)tp * 2 * KVROW];                      \
} while (0)

// Stage chunk's K (16 tokens x 512B) into per-wave LDS slice via
// global_load_lds, with XOR swizzle: LDS(row t, pos p) = global(t, p^t).
#define STAGE_K(PB, TT, BUFP) do {                                              \
  const float* kbase_ = key_cache + ((size_t)(PB) * BS + (TT)) * KVROW + g * DH;\
  float* dst_ = (BUFP);                                                         \
  _Pragma("unroll")                                                             \
  for (int seg = 0; seg < 8; ++seg) {                                           \
    const int t_  = 2 * seg + half;                                             \
    const int sg_ = r32 ^ t_;                                                   \
    __builtin_amdgcn_global_load_lds(                                           \
        (const GAS void*)(kbase_ + (size_t)t_ * KVROW + sg_ * 4),               \
        (LAS void*)(dst_ + seg * 256), 16, 0, 0);                               \
  }                                                                             \
} while (0)

// QK + online softmax for one 16-token chunk. Lane = (token r4, quarter qr).
#define COMPUTE(BUF, TT, ABV) do {                                              \
  const float* kb_ = &Kbuf[w][BUF][0];                                          \
  float acc0 = 0.f, acc1 = 0.f, acc2 = 0.f, acc3 = 0.f;                         \
  _Pragma("unroll")                                                             \
  for (int i = 0; i < 8; ++i) {                                                 \
    const int pos_ = (qr * 8 + i) ^ r4;                                         \
    const float4 kv = *(const float4*)&kb_[r4 * DH + pos_ * 4];                 \
    const float4 q0 = *(const float4*)&q_lds[((0 * 4 + qr) * 9 + i) * 4];       \
    const float4 q1 = *(const float4*)&q_lds[((1 * 4 + qr) * 9 + i) * 4];       \
    const float4 q2 = *(const float4*)&q_lds[((2 * 4 + qr) * 9 + i) * 4];       \
    const float4 q3 = *(const float4*)&q_lds[((3 * 4 + qr) * 9 + i) * 4];       \
    acc0 += kv.x*q0.x + kv.y*q0.y + kv.z*q0.z + kv.w*q0.w;                      \
    acc1 += kv.x*q1.x + kv.y*q1.y + kv.z*q1.z + kv.w*q1.w;                      \
    acc2 += kv.x*q2.x + kv.y*q2.y + kv.z*q2.z + kv.w*q2.w;                      \
    acc3 += kv.x*q3.x + kv.y*q3.y + kv.z*q3.z + kv.w*q3.w;                      \
  }                                                                             \
  float accv[QPK] = {acc0, acc1, acc2, acc3};                                   \
  const bool valid_ = ((TT) + r4) < us_c;                                       \
  float pr_[QPK];                                                               \
  _Pragma("unroll")                                                             \
  for (int qh = 0; qh < QPK; ++qh) {                                            \
    float sc = accv[qh] + __shfl_xor(accv[qh], 16);                             \
    sc += __shfl_xor(sc, 32);                                                   \
    sc += (ABV) * slope[qh];                                                    \
    if (!valid_) sc = NEG;                                                      \
    float cm = sc;                                                              \
    _Pragma("unroll")                                                           \
    for (int off = 1; off < 16; off <<= 1) cm = fmaxf(cm, __shfl_xor(cm, off)); \
    const float mnew = fmaxf(m[qh], cm);                                        \
    const float rs = __expf(m[qh] - mnew);                                      \
    m[qh] = mnew;                                                               \
    pr_[qh] = valid_ ? __expf(sc - mnew) : 0.f;                                 \
    sacc[qh] = sacc[qh] * rs + ((lane < 16) ? pr_[qh] : 0.f);                   \
    O[qh][0] *= rs; O[qh][1] *= rs; O[qh][2] *= rs; O[qh][3] *= rs;             \
  }                                                                             \
  if (lane < 16)                                                                \
    *(float4*)&p_lds[w][r4 * 4] = make_float4(pr_[0], pr_[1], pr_[2], pr_[3]);  \
} while (0)

#define AV(VR) do {                                                             \
  _Pragma("unroll")                                                             \
  for (int tp = 0; tp < 8; ++tp) {                                              \
    const float4 pv = *(const float4*)&p_lds[w][(2 * tp + half) * 4];           \
    const float4 vv = VR[tp];                                                   \
    O[0][0]+=pv.x*vv.x; O[0][1]+=pv.x*vv.y; O[0][2]+=pv.x*vv.z; O[0][3]+=pv.x*vv.w; \
    O[1][0]+=pv.y*vv.x; O[1][1]+=pv.y*vv.y; O[1][2]+=pv.y*vv.z; O[1][3]+=pv.y*vv.w; \
    O[2][0]+=pv.z*vv.x; O[2][1]+=pv.z*vv.y; O[2][2]+=pv.z*vv.z; O[2][3]+=pv.z*vv.w; \
    O[3][0]+=pv.w*vv.x; O[3][1]+=pv.w*vv.y; O[3][2]+=pv.w*vv.z; O[3][3]+=pv.w*vv.w; \
  }                                                                             \
} while (0)

__global__ __launch_bounds__(256, 2)
void pa_partial(const float* __restrict__ query,
                const float* __restrict__ key_cache,
                const float* __restrict__ value_cache,
                const float* __restrict__ alibi_blocks,
                const float* __restrict__ alibi_slopes,
                const int* __restrict__ block_list,
                const int* __restrict__ block_groups,
                const int* __restrict__ block_usage,
                float* __restrict__ Mp, float* __restrict__ Sp,
                float* __restrict__ Op, int U) {
  __shared__ __align__(16) float Kbuf[4][2][CHK * DH];   // 64 KiB: per-wave dbuf
  __shared__ __align__(16) float q_lds[QPK * 4 * 9 * 4]; // padded, conflict-free
  __shared__ __align__(16) float p_lds[4][CHK * QPK];
  __shared__ int ulist[MAXU], pblds[MAXU], uslds[MAXU];
  __shared__ int ucount;

  const int tid  = threadIdx.x;
  const int w    = tid >> 6;
  const int lane = tid & 63;
  const int r32  = lane & 31;
  const int half = lane >> 5;
  const int r4   = lane & 15;
  const int qr   = lane >> 4;
  const int bid  = blockIdx.x;
  const int b    = bid >> 4;          // / (KVH*SPLIT)
  const int g    = (bid >> 1) & 7;
  const int sp   = bid & 1;

  // ---- gather this sequence's block entries (order-preserving) ----
  if (w == 0) {
    int cnt = 0;
    for (int base = 0; base < U; base += 64) {
      const int u = base + lane;
      const bool match = (u < U) && (block_groups[u] == b);
      const unsigned long long mk = __ballot(match);
      if (match) {
        const int pre = __popcll(mk & ((1ull << lane) - 1ull));
        ulist[cnt + pre] = u;
      }
      cnt += __popcll(mk);
    }
    if (lane == 0) ucount = cnt;
    for (int i = lane; i < cnt; i += 64) {
      const int u = ulist[i];
      pblds[i] = block_list[u];
      uslds[i] = block_usage[u];
    }
  }

  // ---- scaled query -> padded LDS layout [qh][quarter][9 granules] ----
  {
    const float* qsrc = query + ((size_t)b * NH + g * QPK) * DH;
    for (int e = tid; e < QPK * DH; e += 256) {
      const int qh = e >> 7, idx = e & 127;
      const int qq = idx >> 5, ii = (idx >> 2) & 7, kk = idx & 3;
      q_lds[((qh * 4 + qq) * 9 + ii) * 4 + kk] = qsrc[e] * SCALEF;
    }
  }

  float slope[QPK];
#pragma unroll
  for (int qh = 0; qh < QPK; ++qh) slope[qh] = alibi_slopes[g * QPK + qh];

  __syncthreads();

  const int nblk = ucount;
  const int nblocks = (nblk > sp) ? ((nblk - 1 - sp) / SPLIT + 1) : 0;

  float m[QPK], sacc[QPK], O[QPK][4];
#pragma unroll
  for (int qh = 0; qh < QPK; ++qh) {
    m[qh] = NEG; sacc[qh] = 0.f;
#pragma unroll
    for (int k = 0; k < 4; ++k) O[qh][k] = 0.f;
  }

  float4 vA[8], vB[8];
  float abA = 0.f, abB = 0.f;
  int u_c = 0, pb_c = 0, us_c = 0;
  const int Tw = w * 32;

  if (nblocks > 0) {  // prologue: V(chunk0)+ab(chunk0) first, then K-stage(chunk0)
    u_c = ulist[sp]; pb_c = pblds[sp]; us_c = uslds[sp];
    LOAD_V(pb_c, Tw, vA);
    abA = alibi_blocks[(size_t)u_c * BS + Tw + r4];
    STAGE_K(pb_c, Tw, &Kbuf[w][0][0]);
  }

  for (int p = 0; p < nblocks; ++p) {
    const bool lastp = (p + 1 >= nblocks);
    int u_n = 0, pb_n = 0, us_n = 0;

    // ===== body A: chunk (block p, h=0), buf0, consumes vA/abA =====
    LOAD_V(pb_c, Tw + CHK, vB);                       // next chunk (same block, h=1)
    abB = alibi_blocks[(size_t)u_c * BS + Tw + CHK + r4];
    __builtin_amdgcn_sched_barrier(0);
    STAGE_K(pb_c, Tw + CHK, &Kbuf[w][1][0]);
    __builtin_amdgcn_sched_barrier(0);
    asm volatile("s_waitcnt vmcnt(17)" ::: "memory"); // K(cur)+V(cur) done; 17 in flight
    __builtin_amdgcn_sched_barrier(0);
    COMPUTE(0, Tw, abA);
    AV(vA);

    // ===== body B: chunk (block p, h=1), buf1, consumes vB/abB =====
    if (!lastp) {
      const int in = sp + (p + 1) * SPLIT;
      u_n = ulist[in]; pb_n = pblds[in]; us_n = uslds[in];
      LOAD_V(pb_n, Tw, vA);
      abA = alibi_blocks[(size_t)u_n * BS + Tw + r4];
    }
    __builtin_amdgcn_sched_barrier(0);
    if (!lastp) STAGE_K(pb_n, Tw, &Kbuf[w][0][0]);
    __builtin_amdgcn_sched_barrier(0);
    if (!lastp) { asm volatile("s_waitcnt vmcnt(17)" ::: "memory"); }
    else        { asm volatile("s_waitcnt vmcnt(0)"  ::: "memory"); }
    __builtin_amdgcn_sched_barrier(0);
    COMPUTE(1, Tw + CHK, abB);
    AV(vB);

    u_c = u_n; pb_c = pb_n; us_c = us_n;
  }

  // ---- per-wave finalize into own (now dead) Kbuf slice ----
  float* cO  = &Kbuf[w][0][0];   // [qh*DH + d]
  float* cMS = &Kbuf[w][1][0];   // [qh]=M, [4+qh]=S
#pragma unroll
  for (int qh = 0; qh < QPK; ++qh) {
    float sv = sacc[qh];
#pragma unroll
    for (int off = 1; off < 64; off <<= 1) sv += __shfl_xor(sv, off);
#pragma unroll
    for (int k = 0; k < 4; ++k) O[qh][k] += __shfl_xor(O[qh][k], 32);
    if (half == 0) {
#pragma unroll
      for (int k = 0; k < 4; ++k) cO[qh * DH + r32 * 4 + k] = O[qh][k];
    }
    if (lane == 0) { cMS[qh] = m[qh]; cMS[4 + qh] = sv; }
  }
  __syncthreads();

  // ---- cross-wave flash combine -> partial (M, S, O) to workspace ----
  for (int e = tid; e < QPK * DH; e += 256) {
    const int qh = e >> 7, d = e & 127;
    float M = NEG;
#pragma unroll
    for (int ww = 0; ww < 4; ++ww) M = fmaxf(M, Kbuf[ww][1][qh]);
    float S = 0.f, Ov = 0.f;
#pragma unroll
    for (int ww = 0; ww < 4; ++ww) {
      const float f = __expf(Kbuf[ww][1][qh] - M);
      S  += f * Kbuf[ww][1][4 + qh];
      Ov += f * Kbuf[ww][0][qh * DH + d];
    }
    const int P = ((b * KVH + g) * QPK + qh) * SPLIT + sp;
    Op[(size_t)P * DH + d] = Ov;
    if (d == 0) { Mp[P] = M; Sp[P] = S; }
  }
}

// Combine the SPLIT partials per (b, head, d).
__global__ __launch_bounds__(256, 1)
void pa_combine(const float* __restrict__ Mp, const float* __restrict__ Sp,
                const float* __restrict__ Op, float* __restrict__ out) {
  const int e  = blockIdx.x * 256 + threadIdx.x;   // b*4096 + h*128 + d
  const int d  = e & 127;
  const int h  = (e >> 7) & 31;
  const int bb = e >> 12;
  const int gg = h >> 2, qh = h & 3;
  const int P  = ((bb * KVH + gg) * QPK + qh) * SPLIT;
  const float M  = fmaxf(Mp[P], Mp[P + 1]);
  const float f0 = __expf(Mp[P] - M), f1 = __expf(Mp[P + 1] - M);
  const float S  = f0 * Sp[P] + f1 * Sp[P + 1];
  out[e] = (f0 * Op[(size_t)P * DH + d] + f1 * Op[(size_t)(P + 1) * DH + d]) / S;
}

extern "C" void kernel_launch(void* const* d_in, const int* in_sizes, int n_in,
                              void* d_out, int out_size, void* d_ws, size_t ws_size,
                              hipStream_t stream) {
  (void)n_in; (void)out_size; (void)ws_size;
  const float* query        = (const float*)d_in[0];
  const float* key_cache    = (const float*)d_in[1];
  const float* value_cache  = (const float*)d_in[2];
  const float* alibi_blocks = (const float*)d_in[3];
  const float* alibi_slopes = (const float*)d_in[4];
  const int*   block_list   = (const int*)d_in[5];
  const int*   block_groups = (const int*)d_in[6];
  const int*   block_usage  = (const int*)d_in[7];
  float*       out          = (float*)d_out;
  const int U = in_sizes[5];

  const int NP = BATCH * KVH * QPK * SPLIT;       // 2048 partials
  float* Mp = (float*)d_ws;
  float* Sp = Mp + NP;
  float* Op = Sp + NP;

  pa_partial<<<dim3(BATCH * KVH * SPLIT), dim3(256), 0, stream>>>(
      query, key_cache, value_cache, alibi_blocks, alibi_slopes,
      block_list, block_groups, block_usage, Mp, Sp, Op, U);

  pa_combine<<<dim3(BATCH * NH * DH / 256), dim3(256), 0, stream>>>(Mp, Sp, Op, out);
}

// Round 5
// 109.247 us; speedup vs baseline: 1.3689x; 1.3689x over previous
//
#include <hip/hip_runtime.h>
#include <stdint.h>

#define BATCH 32
#define NH    32
#define KVH   8
#define QPK   4
#define DH    128
#define BS    128
#define NEG   (-1e30f)
#define SCALEF 0.08838834764831845f  // 1/sqrt(128)
#define MAXU  64
#define NSP   4          // token-quarter split: WGs per (seq, kv-head)
#define CHK   16         // tokens per wave per block
#define KVROW (KVH * DH)

#define GAS __attribute__((address_space(1)))
#define LAS __attribute__((address_space(3)))

// Wave-private 16-token chunk pipeline, 2-wave (128-thread) WGs, 4 WG/CU.
// WG (b,g,s) owns tokens [s*32, s*32+32) of every KV block; wave w owns
// tokens T0 = s*32 + w*16 .. +16. K is staged to LDS via global_load_lds
// with XOR swizzle LDS(row t, slot p) = global(t, p^t); QK lane map =
// (token r16, d-quarter dq) reads slot (dq*8+i)^r16 -> exactly uniform
// across banks (conflict-free). V goes straight to registers (8 x float4,
// 1KB/instr coalesced). Pipeline: top vmcnt(0) waits only K(cur) (issued
// one iteration earlier); V-consume waits leave K(next) in flight.
__global__ __launch_bounds__(128, 2)
void pa_partial(const float* __restrict__ query,
                const float* __restrict__ key_cache,
                const float* __restrict__ value_cache,
                const float* __restrict__ alibi_blocks,
                const float* __restrict__ alibi_slopes,
                const int* __restrict__ block_list,
                const int* __restrict__ block_groups,
                const int* __restrict__ block_usage,
                float* __restrict__ Mp, float* __restrict__ Sp,
                float* __restrict__ Op, int U) {
  __shared__ __align__(16) float Kbuf[2][2][CHK * DH];  // 32 KiB: per-wave dbuf
  __shared__ __align__(16) float q_lds[QPK * DH];       // 2 KiB
  __shared__ __align__(16) float p_lds[2][CHK * QPK];   // 512 B
  __shared__ float combO[2][QPK][DH];                   // 4 KiB
  __shared__ float combM[2][QPK];
  __shared__ float combS[2][QPK];
  __shared__ int ulist[MAXU], pblds[MAXU], uslds[MAXU];
  __shared__ int ucount;

  const int tid  = threadIdx.x;
  const int w    = tid >> 6;
  const int lane = tid & 63;
  const int r32  = lane & 31;   // V: d-granule
  const int half = lane >> 5;   // V: token parity / K-stage row parity
  const int r16  = lane & 15;   // QK: token within chunk
  const int dq   = lane >> 4;   // QK: d-quarter
  const int bid  = blockIdx.x;
  const int b    = bid >> 5;    // / (KVH*NSP)
  const int g    = (bid >> 2) & 7;
  const int s    = bid & 3;
  const int T0   = s * 32 + w * CHK;   // this wave's token offset in each block

  // ---- gather this sequence's block entries (order-preserving) ----
  if (w == 0) {
    int cnt = 0;
    for (int base = 0; base < U; base += 64) {
      const int u = base + lane;
      const bool match = (u < U) && (block_groups[u] == b);
      const unsigned long long mk = __ballot(match);
      if (match) {
        const int pre = __popcll(mk & ((1ull << lane) - 1ull));
        if (cnt + pre < MAXU) ulist[cnt + pre] = u;
      }
      cnt += __popcll(mk);
    }
    if (cnt > MAXU) cnt = MAXU;
    if (lane == 0) ucount = cnt;
    for (int i = lane; i < cnt; i += 64) {
      const int u = ulist[i];
      pblds[i] = block_list[u];
      uslds[i] = block_usage[u];
    }
  }

  // ---- scaled query -> LDS (linear; QK reads are 4-address broadcasts) ----
  {
    const float* qsrc = query + ((size_t)b * NH + g * QPK) * DH;
    for (int e = tid; e < QPK * DH; e += 128) q_lds[e] = qsrc[e] * SCALEF;
  }

  float slope[QPK];
#pragma unroll
  for (int qh = 0; qh < QPK; ++qh) slope[qh] = alibi_slopes[g * QPK + qh];

  __syncthreads();

  const int nblk = ucount;

  float m[QPK], sacc[QPK], O[QPK][4];
#pragma unroll
  for (int qh = 0; qh < QPK; ++qh) {
    m[qh] = NEG; sacc[qh] = 0.f;
#pragma unroll
    for (int k = 0; k < 4; ++k) O[qh][k] = 0.f;
  }

  int cur = 0;
  int u_c = 0, pb_c = 0, us_c = 0;
  if (nblk > 0) {  // prologue: stage K(block 0)
    u_c = ulist[0]; pb_c = pblds[0]; us_c = uslds[0];
    const float* kbase = key_cache + ((size_t)pb_c * BS + T0) * KVROW + g * DH;
    float* dst = &Kbuf[w][0][0];
#pragma unroll
    for (int seg = 0; seg < 8; ++seg) {
      const int t  = 2 * seg + half;
      const int sg = r32 ^ t;
      __builtin_amdgcn_global_load_lds((const GAS void*)(kbase + (size_t)t * KVROW + sg * 4),
                                       (LAS void*)(dst + seg * 256), 16, 0, 0);
    }
  }

  for (int c = 0; c < nblk; ++c) {
    // ---- top wait: K(cur) staged (issued one iteration ago) ----
    __builtin_amdgcn_sched_barrier(0);
    asm volatile("s_waitcnt vmcnt(0)" ::: "memory");
    __builtin_amdgcn_sched_barrier(0);

    // ---- (a) alibi (oldest vmem) + next-block metadata from LDS ----
    const float ab = alibi_blocks[(size_t)u_c * BS + T0 + r16];
    const bool has_nxt = (c + 1 < nblk);
    int u_n = 0, pb_n = 0, us_n = 0;
    if (has_nxt) { u_n = ulist[c + 1]; pb_n = pblds[c + 1]; us_n = uslds[c + 1]; }

    // ---- (b) V(cur) to registers: lane = (d-granule r32, token parity half) ----
    const float* vb = value_cache + ((size_t)pb_c * BS + T0 + half) * KVROW
                    + g * DH + r32 * 4;
    float4 vreg[8];
#pragma unroll
    for (int tp = 0; tp < 8; ++tp)
      vreg[tp] = *(const float4*)&vb[(size_t)tp * 2 * KVROW];

    // ---- (c) stage K(next) into the other buffer ----
    __builtin_amdgcn_sched_barrier(0);
    if (has_nxt) {
      const float* kbase = key_cache + ((size_t)pb_n * BS + T0) * KVROW + g * DH;
      float* dst = &Kbuf[w][cur ^ 1][0];
#pragma unroll
      for (int seg = 0; seg < 8; ++seg) {
        const int t  = 2 * seg + half;
        const int sg = r32 ^ t;
        __builtin_amdgcn_global_load_lds((const GAS void*)(kbase + (size_t)t * KVROW + sg * 4),
                                         (LAS void*)(dst + seg * 256), 16, 0, 0);
      }
    }
    __builtin_amdgcn_sched_barrier(0);

    // ---- (d) QK from Kbuf[w][cur]: lane = (token r16, d-quarter dq) ----
    const float* kb = &Kbuf[w][cur][0];
    float acc[QPK] = {0.f, 0.f, 0.f, 0.f};
#pragma unroll
    for (int i = 0; i < 8; ++i) {
      const int pos = (dq * 8 + i) ^ r16;             // LDS slot (swizzled)
      const float4 kv = *(const float4*)&kb[r16 * DH + pos * 4];
      const int qo = (dq * 8 + i) * 4;                // global d position
#pragma unroll
      for (int qh = 0; qh < QPK; ++qh) {
        const float4 qv = *(const float4*)&q_lds[qh * DH + qo];
        acc[qh] += kv.x * qv.x + kv.y * qv.y + kv.z * qv.z + kv.w * qv.w;
      }
    }

    // ---- (e) online softmax over this wave's 16 tokens ----
    const bool valid = (T0 + r16) < us_c;
    float p[QPK];
#pragma unroll
    for (int qh = 0; qh < QPK; ++qh) {
      float sc = acc[qh] + __shfl_xor(acc[qh], 16);   // sum d-quarters
      sc += __shfl_xor(sc, 32);
      sc += ab * slope[qh];
      if (!valid) sc = NEG;
      float cm = sc;
#pragma unroll
      for (int off = 1; off < 16; off <<= 1) cm = fmaxf(cm, __shfl_xor(cm, off));
      const float mnew = fmaxf(m[qh], cm);
      const float rs   = __expf(m[qh] - mnew);
      m[qh] = mnew;
      p[qh] = valid ? __expf(sc - mnew) : 0.f;
      sacc[qh] = sacc[qh] * rs + ((lane < 16) ? p[qh] : 0.f);
#pragma unroll
      for (int k = 0; k < 4; ++k) O[qh][k] *= rs;
    }
    if (lane < 16)
      *(float4*)&p_lds[w][r16 * 4] = make_float4(p[0], p[1], p[2], p[3]);

    // ---- (f) AV: consume vreg (compiler wait leaves K(next) in flight) ----
#pragma unroll
    for (int tp = 0; tp < 8; ++tp) {
      const float4 pv = *(const float4*)&p_lds[w][(2 * tp + half) * 4];
      const float4 vv = vreg[tp];
      O[0][0]+=pv.x*vv.x; O[0][1]+=pv.x*vv.y; O[0][2]+=pv.x*vv.z; O[0][3]+=pv.x*vv.w;
      O[1][0]+=pv.y*vv.x; O[1][1]+=pv.y*vv.y; O[1][2]+=pv.y*vv.z; O[1][3]+=pv.y*vv.w;
      O[2][0]+=pv.z*vv.x; O[2][1]+=pv.z*vv.y; O[2][2]+=pv.z*vv.z; O[2][3]+=pv.z*vv.w;
      O[3][0]+=pv.w*vv.x; O[3][1]+=pv.w*vv.y; O[3][2]+=pv.w*vv.z; O[3][3]+=pv.w*vv.w;
    }

    u_c = u_n; pb_c = pb_n; us_c = us_n;
    cur ^= 1;
  }

  // ---- per-wave finalize ----
#pragma unroll
  for (int qh = 0; qh < QPK; ++qh) {
    float sv = sacc[qh];
#pragma unroll
    for (int off = 1; off < 64; off <<= 1) sv += __shfl_xor(sv, off);
#pragma unroll
    for (int k = 0; k < 4; ++k) O[qh][k] += __shfl_xor(O[qh][k], 32);
    if (half == 0) {
#pragma unroll
      for (int k = 0; k < 4; ++k) combO[w][qh][r32 * 4 + k] = O[qh][k];
    }
    if (lane == 0) { combM[w][qh] = m[qh]; combS[w][qh] = sv; }
  }
  __syncthreads();

  // ---- cross-wave (2) flash combine -> partial (M,S,O) to workspace ----
  for (int e = tid; e < QPK * DH; e += 128) {
    const int qh = e >> 7, d = e & 127;
    const float M  = fmaxf(combM[0][qh], combM[1][qh]);
    const float f0 = __expf(combM[0][qh] - M);
    const float f1 = __expf(combM[1][qh] - M);
    const float S  = f0 * combS[0][qh] + f1 * combS[1][qh];
    const float Ov = f0 * combO[0][qh][d] + f1 * combO[1][qh][d];
    const int P = ((b * KVH + g) * QPK + qh) * NSP + s;
    Op[(size_t)P * DH + d] = Ov;
    if (d == 0) { Mp[P] = M; Sp[P] = S; }
  }
}

// Combine the NSP partials per (b, head, d).
__global__ __launch_bounds__(256, 1)
void pa_combine(const float* __restrict__ Mp, const float* __restrict__ Sp,
                const float* __restrict__ Op, float* __restrict__ out) {
  const int e  = blockIdx.x * 256 + threadIdx.x;   // b*4096 + h*128 + d
  const int d  = e & 127;
  const int h  = (e >> 7) & 31;
  const int bb = e >> 12;
  const int gg = h >> 2, qh = h & 3;
  const int P  = ((bb * KVH + gg) * QPK + qh) * NSP;
  float M = NEG;
#pragma unroll
  for (int sp = 0; sp < NSP; ++sp) M = fmaxf(M, Mp[P + sp]);
  float S = 0.f, Ov = 0.f;
#pragma unroll
  for (int sp = 0; sp < NSP; ++sp) {
    const float f = __expf(Mp[P + sp] - M);
    S  += f * Sp[P + sp];
    Ov += f * Op[(size_t)(P + sp) * DH + d];
  }
  out[e] = Ov / S;
}

extern "C" void kernel_launch(void* const* d_in, const int* in_sizes, int n_in,
                              void* d_out, int out_size, void* d_ws, size_t ws_size,
                              hipStream_t stream) {
  (void)n_in; (void)out_size; (void)ws_size;
  const float* query        = (const float*)d_in[0];
  const float* key_cache    = (const float*)d_in[1];
  const float* value_cache  = (const float*)d_in[2];
  const float* alibi_blocks = (const float*)d_in[3];
  const float* alibi_slopes = (const float*)d_in[4];
  const int*   block_list   = (const int*)d_in[5];
  const int*   block_groups = (const int*)d_in[6];
  const int*   block_usage  = (const int*)d_in[7];
  float*       out          = (float*)d_out;
  const int U = in_sizes[5];

  const int NP = BATCH * KVH * QPK * NSP;          // 4096 partials
  float* Mp = (float*)d_ws;
  float* Sp = Mp + NP;
  float* Op = Sp + NP;

  pa_partial<<<dim3(BATCH * KVH * NSP), dim3(128), 0, stream>>>(
      query, key_cache, value_cache, alibi_blocks, alibi_slopes,
      block_list, block_groups, block_usage, Mp, Sp, Op, U);

  pa_combine<<<dim3(BATCH * NH * DH / 256), dim3(256), 0, stream>>>(Mp, Sp, Op, out);
}